// Round 16
// baseline (117.624 us; speedup 1.0000x reference)
//
#include <hip/hip_runtime.h>
#include <math.h>

typedef _Float16 hv8 __attribute__((ext_vector_type(8)));
typedef _Float16 hv4 __attribute__((ext_vector_type(4)));
typedef _Float16 hv2 __attribute__((ext_vector_type(2)));
typedef float f32x4 __attribute__((ext_vector_type(4)));

#define LDS_AS(p) ((__attribute__((address_space(3))) void*)(p))
#define GLB_AS(p) ((const __attribute__((address_space(1))) void*)(p))

// single-instruction base-2 exp (bypasses OCML; v_exp_f32 is the native trans op)
__device__ __forceinline__ float fexp2(float x) {
  float r;
  asm("v_exp_f32 %0, %1" : "=v"(r) : "v"(x));
  return r;
}

// ---------------- prep: rope cos/sin table + fp32->fp16 converts, one launch ----------------
__global__ void prep_kernel(const float* __restrict__ x, const float* __restrict__ wq,
                            const float* __restrict__ wk, const float* __restrict__ wv,
                            const float* __restrict__ wo, _Float16* __restrict__ xb,
                            _Float16* __restrict__ wqkv, _Float16* __restrict__ wob,
                            float2* __restrict__ tab) {
  const int bid = blockIdx.x;
  if (bid < 256) {
    const int idx = bid * 256 + threadIdx.x;  // 65536
    const int pos = idx >> 5, i = idx & 31;
    const float freq = exp2f((float)i * (-13.287712379549449f / 32.0f));
    float s, c;
    sincosf((float)pos * freq, &s, &c);
    tab[idx] = make_float2(c, s);
    return;
  }
  const int i = ((bid - 256) * 256 + threadIdx.x) * 4;  // 0 .. 8M-4
  const float* s;
  _Float16* d;
  int r;
  if (i < 4194304) {  // x segment (block-uniform: 1M boundaries)
    s = x; d = xb; r = i;
  } else {
    const int j = i - 4194304;
    const int seg = j >> 20;
    r = j & 1048575;
    s = (seg == 0) ? wq : (seg == 1) ? wk : (seg == 2) ? wv : wo;
    d = (seg < 3) ? (wqkv + (size_t)seg * 1048576) : wob;
  }
  const float4 v = *reinterpret_cast<const float4*>(s + r);
  hv4 o = {(_Float16)v.x, (_Float16)v.y, (_Float16)v.z, (_Float16)v.w};
  *reinterpret_cast<hv4*>(d + r) = o;
}

// ---------------- fused QKV projection GEMM, reg-frag prefetch K-loop ---------------- (R15)
__global__ __launch_bounds__(256, 3) void qkv_gemm_kernel(const _Float16* __restrict__ A,
                                                          const _Float16* __restrict__ B,
                                                          _Float16* __restrict__ QK,
                                                          _Float16* __restrict__ Vt) {
  constexpr int K = 1024;
  __shared__ __align__(16) _Float16 As[128 * 64];
  __shared__ __align__(16) _Float16 Bs[128 * 64];
  const int t = threadIdx.x;
  const int w = t >> 6, lane = t & 63;
  const int wr = w >> 1, wc = w & 1;
  const int g = lane >> 4, lr = lane & 15;
  const int mBase = blockIdx.y * 128, nBase = blockIdx.x * 128;

  f32x4 acc[4][4];
#pragma unroll
  for (int a = 0; a < 4; a++)
#pragma unroll
    for (int bb = 0; bb < 4; bb++) acc[a][bb] = {0.f, 0.f, 0.f, 0.f};

  auto STAGE = [&](int k0) {
#pragma unroll
    for (int i = 0; i < 4; i++) {
      const int s = i * 256 + t;
      const int r = s >> 3;
      const int cs = ((s & 7) ^ (r & 7)) * 8;
      __builtin_amdgcn_global_load_lds(GLB_AS(A + (size_t)(mBase + r) * K + k0 + cs),
                                       LDS_AS(As + s * 8), 16, 0, 0);
      __builtin_amdgcn_global_load_lds(GLB_AS(B + (size_t)(nBase + r) * K + k0 + cs),
                                       LDS_AS(Bs + s * 8), 16, 0, 0);
    }
  };

  STAGE(0);
  for (int kt = 0; kt < K / 64; kt++) {
    __syncthreads();  // implicit vmcnt(0): staging of tile kt complete
    hv8 af[2][4], bfr[2][4];
#pragma unroll
    for (int ks = 0; ks < 2; ks++) {
#pragma unroll
      for (int mi = 0; mi < 4; mi++) {
        const int ra = wr * 64 + mi * 16 + lr;
        af[ks][mi] = *reinterpret_cast<const hv8*>(As + ra * 64 + (((ks * 4 + g) ^ (ra & 7)) * 8));
      }
#pragma unroll
      for (int ni = 0; ni < 4; ni++) {
        const int rb = wc * 64 + ni * 16 + lr;
        bfr[ks][ni] = *reinterpret_cast<const hv8*>(Bs + rb * 64 + (((ks * 4 + g) ^ (rb & 7)) * 8));
      }
    }
    __syncthreads();  // all waves done reading LDS; buffer free for next staging
    if (kt + 1 < K / 64) STAGE((kt + 1) * 64);
#pragma unroll
    for (int ks = 0; ks < 2; ks++)
#pragma unroll
      for (int mi = 0; mi < 4; mi++)
#pragma unroll
        for (int ni = 0; ni < 4; ni++)
          acc[mi][ni] = __builtin_amdgcn_mfma_f32_16x16x32_f16(af[ks][mi], bfr[ks][ni], acc[mi][ni], 0, 0, 0);
  }

  const int rowBase = mBase + wr * 64;
  const int colBase = nBase + wc * 64;
  if (nBase < 2048) {
    // ---- Q|K: plain store to compact QK [4096][2048] ----
#pragma unroll
    for (int mi = 0; mi < 4; mi++) {
#pragma unroll
      for (int j = 0; j < 4; j++) {
        const size_t row = rowBase + mi * 16 + g * 4 + j;
#pragma unroll
        for (int ni = 0; ni < 4; ni++) {
          const int col = colBase + ni * 16 + lr;
          QK[row * 2048 + col] = (_Float16)acc[mi][ni][j];
        }
      }
    }
  } else {
    // ---- V: pi-permuted transpose store to Vt[bh][d][2048] ----
    const int b = rowBase >> 11;
    const int tok0 = rowBase & 2047;
#pragma unroll
    for (int ni = 0; ni < 4; ni++) {
      const int cc = colBase - 2048 + ni * 16 + lr;
      const int h = cc >> 6, d = cc & 63;
      _Float16* vp = Vt + ((size_t)(b * 16 + h) * 64 + d) * 2048 + tok0 + g * 8;
      hv8 o1, o2;
#pragma unroll
      for (int j = 0; j < 4; j++) {
        o1[j] = (_Float16)acc[0][ni][j];
        o1[4 + j] = (_Float16)acc[1][ni][j];
        o2[j] = (_Float16)acc[2][ni][j];
        o2[4 + j] = (_Float16)acc[3][ni][j];
      }
      *reinterpret_cast<hv8*>(vp) = o1;
      *reinterpret_cast<hv8*>(vp + 32) = o2;
    }
  }
}

// ---------------- RoPE on compact QK [4096][2048], table-driven, hv8 ---------------- (R15)
__global__ void rope_qk_kernel(_Float16* __restrict__ QK, const float2* __restrict__ tab) {
  const int idx = blockIdx.x * 256 + threadIdx.x;  // 1M threads
  const int row = idx >> 8;          // 0..4095
  const int c8 = (idx & 255) * 8;    // col (4 rope pairs)
  const int pos = row & 2047;
  const int i0 = (c8 & 63) >> 1;
  const size_t off = (size_t)row * 2048 + c8;
  hv8 v = *reinterpret_cast<const hv8*>(QK + off);
  const float2* tp = tab + pos * 32 + i0;
  const float4 t01 = *reinterpret_cast<const float4*>(tp);
  const float4 t23 = *reinterpret_cast<const float4*>(tp + 2);
  const float c[4] = {t01.x, t01.z, t23.x, t23.z};
  const float s[4] = {t01.y, t01.w, t23.y, t23.w};
#pragma unroll
  for (int k = 0; k < 4; k++) {
    const float e = (float)v[2 * k], o = (float)v[2 * k + 1];
    v[2 * k] = (_Float16)(e * c[k] - o * s[k]);
    v[2 * k + 1] = (_Float16)(e * s[k] + o * c[k]);
  }
  *reinterpret_cast<hv8*>(QK + off) = v;
}

// ---------------- NT GEMM (out-projection), reg-frag prefetch K-loop ---------------- (R15)
template <int BM, typename OutT>
__global__ __launch_bounds__(256, 2) void gemm_nt(const _Float16* __restrict__ A,
                                                  const _Float16* __restrict__ B,
                                                  OutT* __restrict__ C,
                                                  const int M, const int N, const int K) {
  constexpr int MI = BM / 32;
  constexpr int ALOADS = BM / 32;
  __shared__ __align__(16) _Float16 As[BM * 64];
  __shared__ __align__(16) _Float16 Bs[128 * 64];
  const int t = threadIdx.x;
  const int w = t >> 6, lane = t & 63;
  const int wr = w >> 1, wc = w & 1;
  const int g = lane >> 4, lr = lane & 15;
  const int mBase = blockIdx.y * BM, nBase = blockIdx.x * 128;

  f32x4 acc[MI][4];
#pragma unroll
  for (int a = 0; a < MI; a++)
#pragma unroll
    for (int bb = 0; bb < 4; bb++) acc[a][bb] = {0.f, 0.f, 0.f, 0.f};

  auto STAGE = [&](int k0) {
#pragma unroll
    for (int i = 0; i < ALOADS; i++) {
      const int s = i * 256 + t;
      const int r = s >> 3;
      const int cs = ((s & 7) ^ (r & 7)) * 8;
      __builtin_amdgcn_global_load_lds(GLB_AS(A + (size_t)(mBase + r) * K + k0 + cs),
                                       LDS_AS(As + s * 8), 16, 0, 0);
    }
#pragma unroll
    for (int i = 0; i < 4; i++) {
      const int s = i * 256 + t;
      const int r = s >> 3;
      const int cs = ((s & 7) ^ (r & 7)) * 8;
      __builtin_amdgcn_global_load_lds(GLB_AS(B + (size_t)(nBase + r) * K + k0 + cs),
                                       LDS_AS(Bs + s * 8), 16, 0, 0);
    }
  };

  STAGE(0);
  const int NT = K / 64;
  for (int kt = 0; kt < NT; kt++) {
    __syncthreads();  // implicit vmcnt(0): staging of tile kt complete
    hv8 af[2][MI], bfr[2][4];
#pragma unroll
    for (int ks = 0; ks < 2; ks++) {
#pragma unroll
      for (int mi = 0; mi < MI; mi++) {
        const int ra = wr * (BM / 2) + mi * 16 + lr;
        af[ks][mi] = *reinterpret_cast<const hv8*>(As + ra * 64 + (((ks * 4 + g) ^ (ra & 7)) * 8));
      }
#pragma unroll
      for (int ni = 0; ni < 4; ni++) {
        const int rb = wc * 64 + ni * 16 + lr;
        bfr[ks][ni] = *reinterpret_cast<const hv8*>(Bs + rb * 64 + (((ks * 4 + g) ^ (rb & 7)) * 8));
      }
    }
    __syncthreads();  // LDS free
    if (kt + 1 < NT) STAGE((kt + 1) * 64);
#pragma unroll
    for (int ks = 0; ks < 2; ks++)
#pragma unroll
      for (int mi = 0; mi < MI; mi++)
#pragma unroll
        for (int ni = 0; ni < 4; ni++)
          acc[mi][ni] = __builtin_amdgcn_mfma_f32_16x16x32_f16(af[ks][mi], bfr[ks][ni], acc[mi][ni], 0, 0, 0);
  }
#pragma unroll
  for (int mi = 0; mi < MI; mi++) {
#pragma unroll
    for (int j = 0; j < 4; j++) {
      const size_t row = mBase + wr * (BM / 2) + mi * 16 + g * 4 + j;
#pragma unroll
      for (int ni = 0; ni < 4; ni++) {
        const int col = nBase + wc * 64 + ni * 16 + lr;
        C[row * N + col] = (OutT)acc[mi][ni][j];
      }
    }
  }
}

// ---------------- flash causal attention, QBLK=128 (8 waves), 2 blocks/CU ----------------
// One 128-row q-tile per 8-wave block; KV tiles of 64 -> each staged tile feeds 128 q-rows
// (staging bytes / barriers per FLOP halved vs QBLK=64). Grid 512 = 2 blocks/CU = 4
// waves/SIMD. CU balance: co-resident ids (i, i+256) get qt and 15-qt -> per-CU tile work
// = (2qt+2)+(2(15-qt)+2) = 34 for every CU. Per-wave diag flag: mask lanes whenever
// kv0+63 > m0+w*16; fully-future tiles give all -inf -> rm=-inf -> ballot skips rescale,
// p=0 (safe: each row's first tile is valid so mst is finite by then). Double-buffered
// staging, swapped QK^T, in-register exp2 softmax (ballot-gated defer-max, v_exp_f32,
// ones-MFMA row-sum), pi-permuted Vt -> b128 PV A-frags (0 bank conflicts).
__global__ __launch_bounds__(512, 4) void attn_kernel(const _Float16* __restrict__ QK,
                                                      const _Float16* __restrict__ Vt,
                                                      _Float16* __restrict__ O) {
  __shared__ __align__(16) _Float16 Ks[2][64 * 64];
  __shared__ __align__(16) _Float16 Vs[2][64 * 64];
  const int t = threadIdx.x;
  const int w = t >> 6, lane = t & 63;
  const int g = lane >> 4, lr = lane & 15;
  // CU-balanced q-tile mapping (16 q-tiles of 128 rows)
  const int id = blockIdx.x;
  const int j = id >> 8, r = id & 255;
  const int bh = r & 31, base = r >> 5;          // base 0..7
  const int qt = j ? (15 - base) : base;          // 0..15
  const int m0 = qt * 128;
  const int b = bh >> 4, h = bh & 15;
  const _Float16* Qp = QK + (size_t)b * 2048 * 2048 + h * 64;
  const _Float16* Kp = Qp + 1024;
  const _Float16* Vp = Vt + (size_t)bh * 64 * 2048;
  _Float16* Op = O + (size_t)b * 2048 * 1024 + h * 64;

  const int qg = m0 + w * 16 + lr;  // this lane's q row

  // Q B-frag (n=q, k=g*8+i), pre-scaled by (1/8)*log2(e) for exp2-domain softmax
  hv8 qf[2];
#pragma unroll
  for (int ks = 0; ks < 2; ks++) {
    qf[ks] = *reinterpret_cast<const hv8*>(Qp + (size_t)qg * 2048 + ks * 32 + g * 8);
    qf[ks] = qf[ks] * (_Float16)0.18033688f;
  }

  const hv8 onesf = {(_Float16)1.0f, (_Float16)1.0f, (_Float16)1.0f, (_Float16)1.0f,
                     (_Float16)1.0f, (_Float16)1.0f, (_Float16)1.0f, (_Float16)1.0f};

  // stage one 64x64 K tile + one 64x64 V tile (1 load/thread each at 512 threads)
  auto STAGE = [&](int kv0, int bi) {
    const int s = t;              // 0..511
    const int rr = s >> 3;        // 0..63
    const int cs = ((s & 7) ^ (rr & 7)) * 8;
    __builtin_amdgcn_global_load_lds(GLB_AS(Kp + (size_t)(kv0 + rr) * 2048 + cs),
                                     LDS_AS(&Ks[bi][s * 8]), 16, 0, 0);
    __builtin_amdgcn_global_load_lds(GLB_AS(Vp + (size_t)rr * 2048 + kv0 + cs),
                                     LDS_AS(&Vs[bi][s * 8]), 16, 0, 0);
  };

  f32x4 oacc[4];
#pragma unroll
  for (int d = 0; d < 4; d++) oacc[d] = {0.f, 0.f, 0.f, 0.f};
  f32x4 lacc = {0.f, 0.f, 0.f, 0.f};
  float mst = -INFINITY;

  const int nt = 2 * qt + 2;
  STAGE(0, 0);
  int cur = 0;

  for (int tt = 0; tt < nt; tt++) {
    __syncthreads();  // implicit vmcnt(0): tile tt staged; buffer cur^1 free
    if (tt + 1 < nt) STAGE((tt + 1) * 64, cur ^ 1);
    const int kv0 = tt * 64;
    const _Float16* Kb = Ks[cur];
    const _Float16* Vb = Vs[cur];

    // S^T = K Q^T : A = K rows (m=kv), B = Q (n=q). 4 kv-frags x 2 k-steps.
    f32x4 sf[4];
#pragma unroll
    for (int nf = 0; nf < 4; nf++) sf[nf] = {0.f, 0.f, 0.f, 0.f};
#pragma unroll
    for (int ks = 0; ks < 2; ks++)
#pragma unroll
      for (int nf = 0; nf < 4; nf++) {
        const hv8 kf = *reinterpret_cast<const hv8*>(
            Kb + (nf * 16 + lr) * 64 + (((ks * 4 + g) ^ (lr & 7)) * 8));
        sf[nf] = __builtin_amdgcn_mfma_f32_16x16x32_f16(kf, qf[ks], sf[nf], 0, 0, 0);
      }

    // softmax (base-2, in-register, shfl-free steady state); per-wave diag flag
    const bool diag = (kv0 + 63 > m0 + w * 16);
    float p[4][4];
#pragma unroll
    for (int nf = 0; nf < 4; nf++)
#pragma unroll
      for (int jj = 0; jj < 4; jj++) {
        float xv = sf[nf][jj];
        if (diag && (kv0 + nf * 16 + g * 4 + jj > qg)) xv = -INFINITY;
        p[nf][jj] = xv;
      }
    float r4[4];
#pragma unroll
    for (int nf = 0; nf < 4; nf++)
      r4[nf] = fmaxf(fmaxf(p[nf][0], p[nf][1]), fmaxf(p[nf][2], p[nf][3]));
    const float rm = fmaxf(fmaxf(r4[0], r4[1]), fmaxf(r4[2], r4[3]));
    if (!__all(rm <= mst + 8.0f)) {
      float rw = fmaxf(rm, __shfl_xor(rm, 16));
      rw = fmaxf(rw, __shfl_xor(rw, 32));
      const float mn = fmaxf(mst, rw);
      const float corr = fexp2(mst - mn);  // first tile: exp2(-inf)=0
#pragma unroll
      for (int d = 0; d < 4; d++) oacc[d] *= corr;
      lacc *= corr;
      mst = mn;
    }
#pragma unroll
    for (int nf = 0; nf < 4; nf++)
#pragma unroll
      for (int jj = 0; jj < 4; jj++) p[nf][jj] = fexp2(p[nf][jj] - mst);

    // pf[ks][i] = P[qg][kv0 + ks*32 + (i>>2)*16 + g*4 + (i&3)]  (pi-permuted, lane-local)
    hv8 pf[2];
#pragma unroll
    for (int ks = 0; ks < 2; ks++) {
      const auto c0 = __builtin_amdgcn_cvt_pkrtz(p[2 * ks][0], p[2 * ks][1]);
      const auto c1 = __builtin_amdgcn_cvt_pkrtz(p[2 * ks][2], p[2 * ks][3]);
      const auto c2 = __builtin_amdgcn_cvt_pkrtz(p[2 * ks + 1][0], p[2 * ks + 1][1]);
      const auto c3 = __builtin_amdgcn_cvt_pkrtz(p[2 * ks + 1][2], p[2 * ks + 1][3]);
      pf[ks][0] = (_Float16)c0[0]; pf[ks][1] = (_Float16)c0[1];
      pf[ks][2] = (_Float16)c1[0]; pf[ks][3] = (_Float16)c1[1];
      pf[ks][4] = (_Float16)c2[0]; pf[ks][5] = (_Float16)c2[1];
      pf[ks][6] = (_Float16)c3[0]; pf[ks][7] = (_Float16)c3[1];
    }

    // O^T += V^T P^T (b128 swizzled A-frags); l += ones * P
#pragma unroll
    for (int dblk = 0; dblk < 4; dblk++) {
      const int row = dblk * 16 + lr;
#pragma unroll
      for (int ks = 0; ks < 2; ks++) {
        const hv8 vtf = *reinterpret_cast<const hv8*>(
            Vb + row * 64 + (((ks * 4 + g) ^ (row & 7)) * 8));
        oacc[dblk] = __builtin_amdgcn_mfma_f32_16x16x32_f16(vtf, pf[ks], oacc[dblk], 0, 0, 0);
      }
    }
#pragma unroll
    for (int ks = 0; ks < 2; ks++)
      lacc = __builtin_amdgcn_mfma_f32_16x16x32_f16(onesf, pf[ks], lacc, 0, 0, 0);
    cur ^= 1;
  }

  // epilogue: oacc[dblk][j] = O^T[d=dblk*16+g*4+j][qg]; l = lacc[0]
  const float inv = 1.0f / lacc[0];
#pragma unroll
  for (int dblk = 0; dblk < 4; dblk++) {
    hv4 o;
#pragma unroll
    for (int jj = 0; jj < 4; jj++) o[jj] = (_Float16)(oacc[dblk][jj] * inv);
    *reinterpret_cast<hv4*>(Op + (size_t)qg * 1024 + dblk * 16 + g * 4) = o;
  }
}

extern "C" void kernel_launch(void* const* d_in, const int* in_sizes, int n_in,
                              void* d_out, int out_size, void* d_ws, size_t ws_size,
                              hipStream_t stream) {
  const float* x = (const float*)d_in[0];
  const float* wq = (const float*)d_in[1];
  const float* wk = (const float*)d_in[2];
  const float* wv = (const float*)d_in[3];
  const float* wo = (const float*)d_in[4];
  float* out = (float*)d_out;
  char* ws = (char*)d_ws;
  const size_t MB = 1ull << 20;
  _Float16* xb   = (_Float16*)(ws + 0 * MB);   // 8 MB (A operand for QKV gemm)
  _Float16* wqkv = (_Float16*)(ws + 8 * MB);   // 6 MB (wq|wk|wv contiguous rows)
  _Float16* wob  = (_Float16*)(ws + 14 * MB);  // 2 MB
  _Float16* QKb  = (_Float16*)(ws + 16 * MB);  // 16 MB [4096][2048] Q|K compact
  _Float16* Vtb  = (_Float16*)(ws + 32 * MB);  // 8 MB  [32][64][2048] pi-permuted
  float2*   rtab = (float2*)(ws + 40 * MB);    // 512 KB cos/sin table
  _Float16* Ab   = (_Float16*)(ws + 0 * MB);   // 8 MB  (reuses xb after QKV gemm)

  prep_kernel<<<8448, 256, 0, stream>>>(x, wq, wk, wv, wo, xb, wqkv, wob, rtab);

  // fused Q|K|V projection + V-transpose (rope applied separately on compact QK)
  qkv_gemm_kernel<<<dim3(24, 32), 256, 0, stream>>>(xb, wqkv, QKb, Vtb);

  rope_qk_kernel<<<4096, 256, 0, stream>>>(QKb, rtab);

  attn_kernel<<<512, 512, 0, stream>>>(QKb, Vtb, Ab);

  gemm_nt<64, float><<<dim3(8, 64), 256, 0, stream>>>(Ab, wob, out, 4096, 1024, 1024);
}

// Round 17
// 113.071 us; speedup vs baseline: 1.0403x; 1.0403x over previous
//
#include <hip/hip_runtime.h>
#include <math.h>

typedef _Float16 hv8 __attribute__((ext_vector_type(8)));
typedef _Float16 hv4 __attribute__((ext_vector_type(4)));
typedef _Float16 hv2 __attribute__((ext_vector_type(2)));
typedef float f32x4 __attribute__((ext_vector_type(4)));

#define LDS_AS(p) ((__attribute__((address_space(3))) void*)(p))
#define GLB_AS(p) ((const __attribute__((address_space(1))) void*)(p))

// single-instruction base-2 exp (bypasses OCML; v_exp_f32 is the native trans op)
__device__ __forceinline__ float fexp2(float x) {
  float r;
  asm("v_exp_f32 %0, %1" : "=v"(r) : "v"(x));
  return r;
}

// ---------------- prep: rope cos/sin table + fp32->fp16 converts, one launch ----------------
__global__ void prep_kernel(const float* __restrict__ x, const float* __restrict__ wq,
                            const float* __restrict__ wk, const float* __restrict__ wv,
                            const float* __restrict__ wo, _Float16* __restrict__ xb,
                            _Float16* __restrict__ wqkv, _Float16* __restrict__ wob,
                            float2* __restrict__ tab) {
  const int bid = blockIdx.x;
  if (bid < 256) {
    const int idx = bid * 256 + threadIdx.x;  // 65536
    const int pos = idx >> 5, i = idx & 31;
    const float freq = exp2f((float)i * (-13.287712379549449f / 32.0f));
    float s, c;
    sincosf((float)pos * freq, &s, &c);
    tab[idx] = make_float2(c, s);
    return;
  }
  const int i = ((bid - 256) * 256 + threadIdx.x) * 4;  // 0 .. 8M-4
  const float* s;
  _Float16* d;
  int r;
  if (i < 4194304) {  // x segment (block-uniform: 1M boundaries)
    s = x; d = xb; r = i;
  } else {
    const int j = i - 4194304;
    const int seg = j >> 20;
    r = j & 1048575;
    s = (seg == 0) ? wq : (seg == 1) ? wk : (seg == 2) ? wv : wo;
    d = (seg < 3) ? (wqkv + (size_t)seg * 1048576) : wob;
  }
  const float4 v = *reinterpret_cast<const float4*>(s + r);
  hv4 o = {(_Float16)v.x, (_Float16)v.y, (_Float16)v.z, (_Float16)v.w};
  *reinterpret_cast<hv4*>(d + r) = o;
}

// ---------------- fused QKV projection GEMM, reg-frag prefetch K-loop ---------------- (R15)
__global__ __launch_bounds__(256, 3) void qkv_gemm_kernel(const _Float16* __restrict__ A,
                                                          const _Float16* __restrict__ B,
                                                          _Float16* __restrict__ QK,
                                                          _Float16* __restrict__ Vt) {
  constexpr int K = 1024;
  __shared__ __align__(16) _Float16 As[128 * 64];
  __shared__ __align__(16) _Float16 Bs[128 * 64];
  const int t = threadIdx.x;
  const int w = t >> 6, lane = t & 63;
  const int wr = w >> 1, wc = w & 1;
  const int g = lane >> 4, lr = lane & 15;
  const int mBase = blockIdx.y * 128, nBase = blockIdx.x * 128;

  f32x4 acc[4][4];
#pragma unroll
  for (int a = 0; a < 4; a++)
#pragma unroll
    for (int bb = 0; bb < 4; bb++) acc[a][bb] = {0.f, 0.f, 0.f, 0.f};

  auto STAGE = [&](int k0) {
#pragma unroll
    for (int i = 0; i < 4; i++) {
      const int s = i * 256 + t;
      const int r = s >> 3;
      const int cs = ((s & 7) ^ (r & 7)) * 8;
      __builtin_amdgcn_global_load_lds(GLB_AS(A + (size_t)(mBase + r) * K + k0 + cs),
                                       LDS_AS(As + s * 8), 16, 0, 0);
      __builtin_amdgcn_global_load_lds(GLB_AS(B + (size_t)(nBase + r) * K + k0 + cs),
                                       LDS_AS(Bs + s * 8), 16, 0, 0);
    }
  };

  STAGE(0);
  for (int kt = 0; kt < K / 64; kt++) {
    __syncthreads();  // implicit vmcnt(0): staging of tile kt complete
    hv8 af[2][4], bfr[2][4];
#pragma unroll
    for (int ks = 0; ks < 2; ks++) {
#pragma unroll
      for (int mi = 0; mi < 4; mi++) {
        const int ra = wr * 64 + mi * 16 + lr;
        af[ks][mi] = *reinterpret_cast<const hv8*>(As + ra * 64 + (((ks * 4 + g) ^ (ra & 7)) * 8));
      }
#pragma unroll
      for (int ni = 0; ni < 4; ni++) {
        const int rb = wc * 64 + ni * 16 + lr;
        bfr[ks][ni] = *reinterpret_cast<const hv8*>(Bs + rb * 64 + (((ks * 4 + g) ^ (rb & 7)) * 8));
      }
    }
    __syncthreads();  // all waves done reading LDS; buffer free for next staging
    if (kt + 1 < K / 64) STAGE((kt + 1) * 64);
#pragma unroll
    for (int ks = 0; ks < 2; ks++)
#pragma unroll
      for (int mi = 0; mi < 4; mi++)
#pragma unroll
        for (int ni = 0; ni < 4; ni++)
          acc[mi][ni] = __builtin_amdgcn_mfma_f32_16x16x32_f16(af[ks][mi], bfr[ks][ni], acc[mi][ni], 0, 0, 0);
  }

  const int rowBase = mBase + wr * 64;
  const int colBase = nBase + wc * 64;
  if (nBase < 2048) {
    // ---- Q|K: plain store to compact QK [4096][2048] ----
#pragma unroll
    for (int mi = 0; mi < 4; mi++) {
#pragma unroll
      for (int j = 0; j < 4; j++) {
        const size_t row = rowBase + mi * 16 + g * 4 + j;
#pragma unroll
        for (int ni = 0; ni < 4; ni++) {
          const int col = colBase + ni * 16 + lr;
          QK[row * 2048 + col] = (_Float16)acc[mi][ni][j];
        }
      }
    }
  } else {
    // ---- V: pi-permuted transpose store to Vt[bh][d][2048] ----
    const int b = rowBase >> 11;
    const int tok0 = rowBase & 2047;
#pragma unroll
    for (int ni = 0; ni < 4; ni++) {
      const int cc = colBase - 2048 + ni * 16 + lr;
      const int h = cc >> 6, d = cc & 63;
      _Float16* vp = Vt + ((size_t)(b * 16 + h) * 64 + d) * 2048 + tok0 + g * 8;
      hv8 o1, o2;
#pragma unroll
      for (int j = 0; j < 4; j++) {
        o1[j] = (_Float16)acc[0][ni][j];
        o1[4 + j] = (_Float16)acc[1][ni][j];
        o2[j] = (_Float16)acc[2][ni][j];
        o2[4 + j] = (_Float16)acc[3][ni][j];
      }
      *reinterpret_cast<hv8*>(vp) = o1;
      *reinterpret_cast<hv8*>(vp + 32) = o2;
    }
  }
}

// ---------------- RoPE on compact QK [4096][2048], table-driven, hv8 ---------------- (R15)
__global__ void rope_qk_kernel(_Float16* __restrict__ QK, const float2* __restrict__ tab) {
  const int idx = blockIdx.x * 256 + threadIdx.x;  // 1M threads
  const int row = idx >> 8;          // 0..4095
  const int c8 = (idx & 255) * 8;    // col (4 rope pairs)
  const int pos = row & 2047;
  const int i0 = (c8 & 63) >> 1;
  const size_t off = (size_t)row * 2048 + c8;
  hv8 v = *reinterpret_cast<const hv8*>(QK + off);
  const float2* tp = tab + pos * 32 + i0;
  const float4 t01 = *reinterpret_cast<const float4*>(tp);
  const float4 t23 = *reinterpret_cast<const float4*>(tp + 2);
  const float c[4] = {t01.x, t01.z, t23.x, t23.z};
  const float s[4] = {t01.y, t01.w, t23.y, t23.w};
#pragma unroll
  for (int k = 0; k < 4; k++) {
    const float e = (float)v[2 * k], o = (float)v[2 * k + 1];
    v[2 * k] = (_Float16)(e * c[k] - o * s[k]);
    v[2 * k + 1] = (_Float16)(e * s[k] + o * c[k]);
  }
  *reinterpret_cast<hv8*>(QK + off) = v;
}

// ---------------- NT GEMM (out-projection), reg-frag prefetch K-loop ---------------- (R15)
template <int BM, typename OutT>
__global__ __launch_bounds__(256, 2) void gemm_nt(const _Float16* __restrict__ A,
                                                  const _Float16* __restrict__ B,
                                                  OutT* __restrict__ C,
                                                  const int M, const int N, const int K) {
  constexpr int MI = BM / 32;
  constexpr int ALOADS = BM / 32;
  __shared__ __align__(16) _Float16 As[BM * 64];
  __shared__ __align__(16) _Float16 Bs[128 * 64];
  const int t = threadIdx.x;
  const int w = t >> 6, lane = t & 63;
  const int wr = w >> 1, wc = w & 1;
  const int g = lane >> 4, lr = lane & 15;
  const int mBase = blockIdx.y * BM, nBase = blockIdx.x * 128;

  f32x4 acc[MI][4];
#pragma unroll
  for (int a = 0; a < MI; a++)
#pragma unroll
    for (int bb = 0; bb < 4; bb++) acc[a][bb] = {0.f, 0.f, 0.f, 0.f};

  auto STAGE = [&](int k0) {
#pragma unroll
    for (int i = 0; i < ALOADS; i++) {
      const int s = i * 256 + t;
      const int r = s >> 3;
      const int cs = ((s & 7) ^ (r & 7)) * 8;
      __builtin_amdgcn_global_load_lds(GLB_AS(A + (size_t)(mBase + r) * K + k0 + cs),
                                       LDS_AS(As + s * 8), 16, 0, 0);
    }
#pragma unroll
    for (int i = 0; i < 4; i++) {
      const int s = i * 256 + t;
      const int r = s >> 3;
      const int cs = ((s & 7) ^ (r & 7)) * 8;
      __builtin_amdgcn_global_load_lds(GLB_AS(B + (size_t)(nBase + r) * K + k0 + cs),
                                       LDS_AS(Bs + s * 8), 16, 0, 0);
    }
  };

  STAGE(0);
  const int NT = K / 64;
  for (int kt = 0; kt < NT; kt++) {
    __syncthreads();  // implicit vmcnt(0): staging of tile kt complete
    hv8 af[2][MI], bfr[2][4];
#pragma unroll
    for (int ks = 0; ks < 2; ks++) {
#pragma unroll
      for (int mi = 0; mi < MI; mi++) {
        const int ra = wr * (BM / 2) + mi * 16 + lr;
        af[ks][mi] = *reinterpret_cast<const hv8*>(As + ra * 64 + (((ks * 4 + g) ^ (ra & 7)) * 8));
      }
#pragma unroll
      for (int ni = 0; ni < 4; ni++) {
        const int rb = wc * 64 + ni * 16 + lr;
        bfr[ks][ni] = *reinterpret_cast<const hv8*>(Bs + rb * 64 + (((ks * 4 + g) ^ (rb & 7)) * 8));
      }
    }
    __syncthreads();  // LDS free
    if (kt + 1 < NT) STAGE((kt + 1) * 64);
#pragma unroll
    for (int ks = 0; ks < 2; ks++)
#pragma unroll
      for (int mi = 0; mi < MI; mi++)
#pragma unroll
        for (int ni = 0; ni < 4; ni++)
          acc[mi][ni] = __builtin_amdgcn_mfma_f32_16x16x32_f16(af[ks][mi], bfr[ks][ni], acc[mi][ni], 0, 0, 0);
  }
#pragma unroll
  for (int mi = 0; mi < MI; mi++) {
#pragma unroll
    for (int j = 0; j < 4; j++) {
      const size_t row = mBase + wr * (BM / 2) + mi * 16 + g * 4 + j;
#pragma unroll
      for (int ni = 0; ni < 4; ni++) {
        const int col = nBase + wc * 64 + ni * 16 + lr;
        C[row * N + col] = (OutT)acc[mi][ni][j];
      }
    }
  }
}

// ---------------- flash causal attention, QBLK=128 (8 waves), 2 blocks/CU ----------------
// R16 structure; launch_bounds 2nd arg corrected to 2: hipcc treats it as min BLOCKS/CU
// (CUDA semantics — R16's (512,4) forced 8 waves/SIMD -> 64-reg budget -> VGPR 36 + spill).
// (512,2) = 16 waves/CU = 4 waves/SIMD = 128-reg budget, matching the ~100-VGPR liveness.
// Each staged 64-wide K/V tile feeds 128 q-rows (FETCH 70->12 MB verified in R16).
// CU balance: co-resident ids (i, i+256) get qt and 15-qt -> 34 tile-units per CU.
__global__ __launch_bounds__(512, 2) void attn_kernel(const _Float16* __restrict__ QK,
                                                      const _Float16* __restrict__ Vt,
                                                      _Float16* __restrict__ O) {
  __shared__ __align__(16) _Float16 Ks[2][64 * 64];
  __shared__ __align__(16) _Float16 Vs[2][64 * 64];
  const int t = threadIdx.x;
  const int w = t >> 6, lane = t & 63;
  const int g = lane >> 4, lr = lane & 15;
  // CU-balanced q-tile mapping (16 q-tiles of 128 rows)
  const int id = blockIdx.x;
  const int j = id >> 8, r = id & 255;
  const int bh = r & 31, base = r >> 5;          // base 0..7
  const int qt = j ? (15 - base) : base;          // 0..15
  const int m0 = qt * 128;
  const int b = bh >> 4, h = bh & 15;
  const _Float16* Qp = QK + (size_t)b * 2048 * 2048 + h * 64;
  const _Float16* Kp = Qp + 1024;
  const _Float16* Vp = Vt + (size_t)bh * 64 * 2048;
  _Float16* Op = O + (size_t)b * 2048 * 1024 + h * 64;

  const int qg = m0 + w * 16 + lr;  // this lane's q row

  // Q B-frag (n=q, k=g*8+i), pre-scaled by (1/8)*log2(e) for exp2-domain softmax
  hv8 qf[2];
#pragma unroll
  for (int ks = 0; ks < 2; ks++) {
    qf[ks] = *reinterpret_cast<const hv8*>(Qp + (size_t)qg * 2048 + ks * 32 + g * 8);
    qf[ks] = qf[ks] * (_Float16)0.18033688f;
  }

  const hv8 onesf = {(_Float16)1.0f, (_Float16)1.0f, (_Float16)1.0f, (_Float16)1.0f,
                     (_Float16)1.0f, (_Float16)1.0f, (_Float16)1.0f, (_Float16)1.0f};

  // stage one 64x64 K tile + one 64x64 V tile (1 load/thread each at 512 threads)
  auto STAGE = [&](int kv0, int bi) {
    const int s = t;              // 0..511
    const int rr = s >> 3;        // 0..63
    const int cs = ((s & 7) ^ (rr & 7)) * 8;
    __builtin_amdgcn_global_load_lds(GLB_AS(Kp + (size_t)(kv0 + rr) * 2048 + cs),
                                     LDS_AS(&Ks[bi][s * 8]), 16, 0, 0);
    __builtin_amdgcn_global_load_lds(GLB_AS(Vp + (size_t)rr * 2048 + kv0 + cs),
                                     LDS_AS(&Vs[bi][s * 8]), 16, 0, 0);
  };

  f32x4 oacc[4];
#pragma unroll
  for (int d = 0; d < 4; d++) oacc[d] = {0.f, 0.f, 0.f, 0.f};
  f32x4 lacc = {0.f, 0.f, 0.f, 0.f};
  float mst = -INFINITY;

  const int nt = 2 * qt + 2;
  STAGE(0, 0);
  int cur = 0;

  for (int tt = 0; tt < nt; tt++) {
    __syncthreads();  // implicit vmcnt(0): tile tt staged; buffer cur^1 free
    if (tt + 1 < nt) STAGE((tt + 1) * 64, cur ^ 1);
    const int kv0 = tt * 64;
    const _Float16* Kb = Ks[cur];
    const _Float16* Vb = Vs[cur];

    // S^T = K Q^T : A = K rows (m=kv), B = Q (n=q). 4 kv-frags x 2 k-steps.
    f32x4 sf[4];
#pragma unroll
    for (int nf = 0; nf < 4; nf++) sf[nf] = {0.f, 0.f, 0.f, 0.f};
#pragma unroll
    for (int ks = 0; ks < 2; ks++)
#pragma unroll
      for (int nf = 0; nf < 4; nf++) {
        const hv8 kf = *reinterpret_cast<const hv8*>(
            Kb + (nf * 16 + lr) * 64 + (((ks * 4 + g) ^ (lr & 7)) * 8));
        sf[nf] = __builtin_amdgcn_mfma_f32_16x16x32_f16(kf, qf[ks], sf[nf], 0, 0, 0);
      }

    // softmax (base-2, in-register, shfl-free steady state); per-wave diag flag
    const bool diag = (kv0 + 63 > m0 + w * 16);
    float p[4][4];
#pragma unroll
    for (int nf = 0; nf < 4; nf++)
#pragma unroll
      for (int jj = 0; jj < 4; jj++) {
        float xv = sf[nf][jj];
        if (diag && (kv0 + nf * 16 + g * 4 + jj > qg)) xv = -INFINITY;
        p[nf][jj] = xv;
      }
    float r4[4];
#pragma unroll
    for (int nf = 0; nf < 4; nf++)
      r4[nf] = fmaxf(fmaxf(p[nf][0], p[nf][1]), fmaxf(p[nf][2], p[nf][3]));
    const float rm = fmaxf(fmaxf(r4[0], r4[1]), fmaxf(r4[2], r4[3]));
    if (!__all(rm <= mst + 8.0f)) {
      float rw = fmaxf(rm, __shfl_xor(rm, 16));
      rw = fmaxf(rw, __shfl_xor(rw, 32));
      const float mn = fmaxf(mst, rw);
      const float corr = fexp2(mst - mn);  // first tile: exp2(-inf)=0
#pragma unroll
      for (int d = 0; d < 4; d++) oacc[d] *= corr;
      lacc *= corr;
      mst = mn;
    }
#pragma unroll
    for (int nf = 0; nf < 4; nf++)
#pragma unroll
      for (int jj = 0; jj < 4; jj++) p[nf][jj] = fexp2(p[nf][jj] - mst);

    // pf[ks][i] = P[qg][kv0 + ks*32 + (i>>2)*16 + g*4 + (i&3)]  (pi-permuted, lane-local)
    hv8 pf[2];
#pragma unroll
    for (int ks = 0; ks < 2; ks++) {
      const auto c0 = __builtin_amdgcn_cvt_pkrtz(p[2 * ks][0], p[2 * ks][1]);
      const auto c1 = __builtin_amdgcn_cvt_pkrtz(p[2 * ks][2], p[2 * ks][3]);
      const auto c2 = __builtin_amdgcn_cvt_pkrtz(p[2 * ks + 1][0], p[2 * ks + 1][1]);
      const auto c3 = __builtin_amdgcn_cvt_pkrtz(p[2 * ks + 1][2], p[2 * ks + 1][3]);
      pf[ks][0] = (_Float16)c0[0]; pf[ks][1] = (_Float16)c0[1];
      pf[ks][2] = (_Float16)c1[0]; pf[ks][3] = (_Float16)c1[1];
      pf[ks][4] = (_Float16)c2[0]; pf[ks][5] = (_Float16)c2[1];
      pf[ks][6] = (_Float16)c3[0]; pf[ks][7] = (_Float16)c3[1];
    }

    // O^T += V^T P^T (b128 swizzled A-frags); l += ones * P
#pragma unroll
    for (int dblk = 0; dblk < 4; dblk++) {
      const int row = dblk * 16 + lr;
#pragma unroll
      for (int ks = 0; ks < 2; ks++) {
        const hv8 vtf = *reinterpret_cast<const hv8*>(
            Vb + row * 64 + (((ks * 4 + g) ^ (row & 7)) * 8));
        oacc[dblk] = __builtin_amdgcn_mfma_f32_16x16x32_f16(vtf, pf[ks], oacc[dblk], 0, 0, 0);
      }
    }
#pragma unroll
    for (int ks = 0; ks < 2; ks++)
      lacc = __builtin_amdgcn_mfma_f32_16x16x32_f16(onesf, pf[ks], lacc, 0, 0, 0);
    cur ^= 1;
  }

  // epilogue: oacc[dblk][j] = O^T[d=dblk*16+g*4+j][qg]; l = lacc[0]
  const float inv = 1.0f / lacc[0];
#pragma unroll
  for (int dblk = 0; dblk < 4; dblk++) {
    hv4 o;
#pragma unroll
    for (int jj = 0; jj < 4; jj++) o[jj] = (_Float16)(oacc[dblk][jj] * inv);
    *reinterpret_cast<hv4*>(Op + (size_t)qg * 1024 + dblk * 16 + g * 4) = o;
  }
}

extern "C" void kernel_launch(void* const* d_in, const int* in_sizes, int n_in,
                              void* d_out, int out_size, void* d_ws, size_t ws_size,
                              hipStream_t stream) {
  const float* x = (const float*)d_in[0];
  const float* wq = (const float*)d_in[1];
  const float* wk = (const float*)d_in[2];
  const float* wv = (const float*)d_in[3];
  const float* wo = (const float*)d_in[4];
  float* out = (float*)d_out;
  char* ws = (char*)d_ws;
  const size_t MB = 1ull << 20;
  _Float16* xb   = (_Float16*)(ws + 0 * MB);   // 8 MB (A operand for QKV gemm)
  _Float16* wqkv = (_Float16*)(ws + 8 * MB);   // 6 MB (wq|wk|wv contiguous rows)
  _Float16* wob  = (_Float16*)(ws + 14 * MB);  // 2 MB
  _Float16* QKb  = (_Float16*)(ws + 16 * MB);  // 16 MB [4096][2048] Q|K compact
  _Float16* Vtb  = (_Float16*)(ws + 32 * MB);  // 8 MB  [32][64][2048] pi-permuted
  float2*   rtab = (float2*)(ws + 40 * MB);    // 512 KB cos/sin table
  _Float16* Ab   = (_Float16*)(ws + 0 * MB);   // 8 MB  (reuses xb after QKV gemm)

  prep_kernel<<<8448, 256, 0, stream>>>(x, wq, wk, wv, wo, xb, wqkv, wob, rtab);

  // fused Q|K|V projection + V-transpose (rope applied separately on compact QK)
  qkv_gemm_kernel<<<dim3(24, 32), 256, 0, stream>>>(xb, wqkv, QKb, Vtb);

  rope_qk_kernel<<<4096, 256, 0, stream>>>(QKb, rtab);

  attn_kernel<<<512, 512, 0, stream>>>(QKb, Vtb, Ab);

  gemm_nt<64, float><<<dim3(8, 64), 256, 0, stream>>>(Ab, wob, out, 4096, 1024, 1024);
}

// Round 18
// 105.208 us; speedup vs baseline: 1.1180x; 1.0747x over previous
//
#include <hip/hip_runtime.h>
#include <math.h>

typedef _Float16 hv8 __attribute__((ext_vector_type(8)));
typedef _Float16 hv4 __attribute__((ext_vector_type(4)));
typedef _Float16 hv2 __attribute__((ext_vector_type(2)));
typedef float f32x4 __attribute__((ext_vector_type(4)));

#define LDS_AS(p) ((__attribute__((address_space(3))) void*)(p))
#define GLB_AS(p) ((const __attribute__((address_space(1))) void*)(p))

// single-instruction base-2 exp (bypasses OCML; v_exp_f32 is the native trans op)
__device__ __forceinline__ float fexp2(float x) {
  float r;
  asm("v_exp_f32 %0, %1" : "=v"(r) : "v"(x));
  return r;
}

// ---------------- prep: rope cos/sin table + fp32->fp16 converts, one launch ----------------
__global__ void prep_kernel(const float* __restrict__ x, const float* __restrict__ wq,
                            const float* __restrict__ wk, const float* __restrict__ wv,
                            const float* __restrict__ wo, _Float16* __restrict__ xb,
                            _Float16* __restrict__ wqkv, _Float16* __restrict__ wob,
                            float2* __restrict__ tab) {
  const int bid = blockIdx.x;
  if (bid < 256) {
    const int idx = bid * 256 + threadIdx.x;  // 65536
    const int pos = idx >> 5, i = idx & 31;
    const float freq = exp2f((float)i * (-13.287712379549449f / 32.0f));
    float s, c;
    sincosf((float)pos * freq, &s, &c);
    tab[idx] = make_float2(c, s);
    return;
  }
  const int i = ((bid - 256) * 256 + threadIdx.x) * 4;  // 0 .. 8M-4
  const float* s;
  _Float16* d;
  int r;
  if (i < 4194304) {  // x segment (block-uniform: 1M boundaries)
    s = x; d = xb; r = i;
  } else {
    const int j = i - 4194304;
    const int seg = j >> 20;
    r = j & 1048575;
    s = (seg == 0) ? wq : (seg == 1) ? wk : (seg == 2) ? wv : wo;
    d = (seg < 3) ? (wqkv + (size_t)seg * 1048576) : wob;
  }
  const float4 v = *reinterpret_cast<const float4*>(s + r);
  hv4 o = {(_Float16)v.x, (_Float16)v.y, (_Float16)v.z, (_Float16)v.w};
  *reinterpret_cast<hv4*>(d + r) = o;
}

// ---------------- fused QKV projection GEMM, reg-frag prefetch K-loop ---------------- (R15)
__global__ __launch_bounds__(256, 3) void qkv_gemm_kernel(const _Float16* __restrict__ A,
                                                          const _Float16* __restrict__ B,
                                                          _Float16* __restrict__ QK,
                                                          _Float16* __restrict__ Vt) {
  constexpr int K = 1024;
  __shared__ __align__(16) _Float16 As[128 * 64];
  __shared__ __align__(16) _Float16 Bs[128 * 64];
  const int t = threadIdx.x;
  const int w = t >> 6, lane = t & 63;
  const int wr = w >> 1, wc = w & 1;
  const int g = lane >> 4, lr = lane & 15;
  const int mBase = blockIdx.y * 128, nBase = blockIdx.x * 128;

  f32x4 acc[4][4];
#pragma unroll
  for (int a = 0; a < 4; a++)
#pragma unroll
    for (int bb = 0; bb < 4; bb++) acc[a][bb] = {0.f, 0.f, 0.f, 0.f};

  auto STAGE = [&](int k0) {
#pragma unroll
    for (int i = 0; i < 4; i++) {
      const int s = i * 256 + t;
      const int r = s >> 3;
      const int cs = ((s & 7) ^ (r & 7)) * 8;
      __builtin_amdgcn_global_load_lds(GLB_AS(A + (size_t)(mBase + r) * K + k0 + cs),
                                       LDS_AS(As + s * 8), 16, 0, 0);
      __builtin_amdgcn_global_load_lds(GLB_AS(B + (size_t)(nBase + r) * K + k0 + cs),
                                       LDS_AS(Bs + s * 8), 16, 0, 0);
    }
  };

  STAGE(0);
  for (int kt = 0; kt < K / 64; kt++) {
    __syncthreads();  // implicit vmcnt(0): staging of tile kt complete
    hv8 af[2][4], bfr[2][4];
#pragma unroll
    for (int ks = 0; ks < 2; ks++) {
#pragma unroll
      for (int mi = 0; mi < 4; mi++) {
        const int ra = wr * 64 + mi * 16 + lr;
        af[ks][mi] = *reinterpret_cast<const hv8*>(As + ra * 64 + (((ks * 4 + g) ^ (ra & 7)) * 8));
      }
#pragma unroll
      for (int ni = 0; ni < 4; ni++) {
        const int rb = wc * 64 + ni * 16 + lr;
        bfr[ks][ni] = *reinterpret_cast<const hv8*>(Bs + rb * 64 + (((ks * 4 + g) ^ (rb & 7)) * 8));
      }
    }
    __syncthreads();  // all waves done reading LDS; buffer free for next staging
    if (kt + 1 < K / 64) STAGE((kt + 1) * 64);
#pragma unroll
    for (int ks = 0; ks < 2; ks++)
#pragma unroll
      for (int mi = 0; mi < 4; mi++)
#pragma unroll
        for (int ni = 0; ni < 4; ni++)
          acc[mi][ni] = __builtin_amdgcn_mfma_f32_16x16x32_f16(af[ks][mi], bfr[ks][ni], acc[mi][ni], 0, 0, 0);
  }

  const int rowBase = mBase + wr * 64;
  const int colBase = nBase + wc * 64;
  if (nBase < 2048) {
    // ---- Q|K: plain store to compact QK [4096][2048] ----
#pragma unroll
    for (int mi = 0; mi < 4; mi++) {
#pragma unroll
      for (int j = 0; j < 4; j++) {
        const size_t row = rowBase + mi * 16 + g * 4 + j;
#pragma unroll
        for (int ni = 0; ni < 4; ni++) {
          const int col = colBase + ni * 16 + lr;
          QK[row * 2048 + col] = (_Float16)acc[mi][ni][j];
        }
      }
    }
  } else {
    // ---- V: pi-permuted transpose store to Vt[bh][d][2048] ----
    const int b = rowBase >> 11;
    const int tok0 = rowBase & 2047;
#pragma unroll
    for (int ni = 0; ni < 4; ni++) {
      const int cc = colBase - 2048 + ni * 16 + lr;
      const int h = cc >> 6, d = cc & 63;
      _Float16* vp = Vt + ((size_t)(b * 16 + h) * 64 + d) * 2048 + tok0 + g * 8;
      hv8 o1, o2;
#pragma unroll
      for (int j = 0; j < 4; j++) {
        o1[j] = (_Float16)acc[0][ni][j];
        o1[4 + j] = (_Float16)acc[1][ni][j];
        o2[j] = (_Float16)acc[2][ni][j];
        o2[4 + j] = (_Float16)acc[3][ni][j];
      }
      *reinterpret_cast<hv8*>(vp) = o1;
      *reinterpret_cast<hv8*>(vp + 32) = o2;
    }
  }
}

// ---------------- RoPE on compact QK [4096][2048], table-driven, hv8 ---------------- (R15)
__global__ void rope_qk_kernel(_Float16* __restrict__ QK, const float2* __restrict__ tab) {
  const int idx = blockIdx.x * 256 + threadIdx.x;  // 1M threads
  const int row = idx >> 8;          // 0..4095
  const int c8 = (idx & 255) * 8;    // col (4 rope pairs)
  const int pos = row & 2047;
  const int i0 = (c8 & 63) >> 1;
  const size_t off = (size_t)row * 2048 + c8;
  hv8 v = *reinterpret_cast<const hv8*>(QK + off);
  const float2* tp = tab + pos * 32 + i0;
  const float4 t01 = *reinterpret_cast<const float4*>(tp);
  const float4 t23 = *reinterpret_cast<const float4*>(tp + 2);
  const float c[4] = {t01.x, t01.z, t23.x, t23.z};
  const float s[4] = {t01.y, t01.w, t23.y, t23.w};
#pragma unroll
  for (int k = 0; k < 4; k++) {
    const float e = (float)v[2 * k], o = (float)v[2 * k + 1];
    v[2 * k] = (_Float16)(e * c[k] - o * s[k]);
    v[2 * k + 1] = (_Float16)(e * s[k] + o * c[k]);
  }
  *reinterpret_cast<hv8*>(QK + off) = v;
}

// ---------------- NT GEMM (out-projection), reg-frag prefetch K-loop ---------------- (R15)
template <int BM, typename OutT>
__global__ __launch_bounds__(256, 2) void gemm_nt(const _Float16* __restrict__ A,
                                                  const _Float16* __restrict__ B,
                                                  OutT* __restrict__ C,
                                                  const int M, const int N, const int K) {
  constexpr int MI = BM / 32;
  constexpr int ALOADS = BM / 32;
  __shared__ __align__(16) _Float16 As[BM * 64];
  __shared__ __align__(16) _Float16 Bs[128 * 64];
  const int t = threadIdx.x;
  const int w = t >> 6, lane = t & 63;
  const int wr = w >> 1, wc = w & 1;
  const int g = lane >> 4, lr = lane & 15;
  const int mBase = blockIdx.y * BM, nBase = blockIdx.x * 128;

  f32x4 acc[MI][4];
#pragma unroll
  for (int a = 0; a < MI; a++)
#pragma unroll
    for (int bb = 0; bb < 4; bb++) acc[a][bb] = {0.f, 0.f, 0.f, 0.f};

  auto STAGE = [&](int k0) {
#pragma unroll
    for (int i = 0; i < ALOADS; i++) {
      const int s = i * 256 + t;
      const int r = s >> 3;
      const int cs = ((s & 7) ^ (r & 7)) * 8;
      __builtin_amdgcn_global_load_lds(GLB_AS(A + (size_t)(mBase + r) * K + k0 + cs),
                                       LDS_AS(As + s * 8), 16, 0, 0);
    }
#pragma unroll
    for (int i = 0; i < 4; i++) {
      const int s = i * 256 + t;
      const int r = s >> 3;
      const int cs = ((s & 7) ^ (r & 7)) * 8;
      __builtin_amdgcn_global_load_lds(GLB_AS(B + (size_t)(nBase + r) * K + k0 + cs),
                                       LDS_AS(Bs + s * 8), 16, 0, 0);
    }
  };

  STAGE(0);
  const int NT = K / 64;
  for (int kt = 0; kt < NT; kt++) {
    __syncthreads();  // implicit vmcnt(0): staging of tile kt complete
    hv8 af[2][MI], bfr[2][4];
#pragma unroll
    for (int ks = 0; ks < 2; ks++) {
#pragma unroll
      for (int mi = 0; mi < MI; mi++) {
        const int ra = wr * (BM / 2) + mi * 16 + lr;
        af[ks][mi] = *reinterpret_cast<const hv8*>(As + ra * 64 + (((ks * 4 + g) ^ (ra & 7)) * 8));
      }
#pragma unroll
      for (int ni = 0; ni < 4; ni++) {
        const int rb = wc * 64 + ni * 16 + lr;
        bfr[ks][ni] = *reinterpret_cast<const hv8*>(Bs + rb * 64 + (((ks * 4 + g) ^ (rb & 7)) * 8));
      }
    }
    __syncthreads();  // LDS free
    if (kt + 1 < NT) STAGE((kt + 1) * 64);
#pragma unroll
    for (int ks = 0; ks < 2; ks++)
#pragma unroll
      for (int mi = 0; mi < MI; mi++)
#pragma unroll
        for (int ni = 0; ni < 4; ni++)
          acc[mi][ni] = __builtin_amdgcn_mfma_f32_16x16x32_f16(af[ks][mi], bfr[ks][ni], acc[mi][ni], 0, 0, 0);
  }
#pragma unroll
  for (int mi = 0; mi < MI; mi++) {
#pragma unroll
    for (int j = 0; j < 4; j++) {
      const size_t row = mBase + wr * (BM / 2) + mi * 16 + g * 4 + j;
#pragma unroll
      for (int ni = 0; ni < 4; ni++) {
        const int col = nBase + wc * 64 + ni * 16 + lr;
        C[row * N + col] = (OutT)acc[mi][ni][j];
      }
    }
  }
}

// ---------------- flash causal attention, 4 blocks/CU, CU-balanced qt mapping ----------------
// R15 structure (QBLK=64, 4 waves, (256,4) — the measured best; R16/R17's QBLK=128 spilled
// under hipcc's block-based launch-bounds budget and regressed). Added T5 s_setprio(1)
// around the MFMA clusters: 4 independent blocks/CU at different loop phases = the regime
// where setprio measured +4-7% (m191); null only in barrier-lockstep GEMMs (m190).
__global__ __launch_bounds__(256, 4) void attn_kernel(const _Float16* __restrict__ QK,
                                                      const _Float16* __restrict__ Vt,
                                                      _Float16* __restrict__ O) {
  __shared__ __align__(16) _Float16 Ks[2][64 * 64];
  __shared__ __align__(16) _Float16 Vs[2][64 * 64];
  const int t = threadIdx.x;
  const int w = t >> 6, lane = t & 63;
  const int g = lane >> 4, lr = lane & 15;
  // CU-balanced q-tile mapping
  const int id = blockIdx.x;
  const int j = id >> 8, r = id & 255;
  const int bh = r & 31, base = r >> 5;
  const int half = j >> 1;
  const int qt = (j & 1) ? (31 - base - 8 * half) : (base + 8 * half);
  const int m0 = qt * 64;
  const int b = bh >> 4, h = bh & 15;
  const _Float16* Qp = QK + (size_t)b * 2048 * 2048 + h * 64;
  const _Float16* Kp = Qp + 1024;
  const _Float16* Vp = Vt + (size_t)bh * 64 * 2048;
  _Float16* Op = O + (size_t)b * 2048 * 1024 + h * 64;

  const int qg = m0 + w * 16 + lr;  // this lane's q row

  // Q B-frag (n=q, k=g*8+i), pre-scaled by (1/8)*log2(e) for exp2-domain softmax
  hv8 qf[2];
#pragma unroll
  for (int ks = 0; ks < 2; ks++) {
    qf[ks] = *reinterpret_cast<const hv8*>(Qp + (size_t)qg * 2048 + ks * 32 + g * 8);
    qf[ks] = qf[ks] * (_Float16)0.18033688f;
  }

  const hv8 onesf = {(_Float16)1.0f, (_Float16)1.0f, (_Float16)1.0f, (_Float16)1.0f,
                     (_Float16)1.0f, (_Float16)1.0f, (_Float16)1.0f, (_Float16)1.0f};

  auto STAGE = [&](int kv0, int bi) {
#pragma unroll
    for (int i = 0; i < 2; i++) {
      const int s = i * 256 + t;
      const int rr = s >> 3;
      const int cs = ((s & 7) ^ (rr & 7)) * 8;
      __builtin_amdgcn_global_load_lds(GLB_AS(Kp + (size_t)(kv0 + rr) * 2048 + cs),
                                       LDS_AS(&Ks[bi][s * 8]), 16, 0, 0);
      __builtin_amdgcn_global_load_lds(GLB_AS(Vp + (size_t)rr * 2048 + kv0 + cs),
                                       LDS_AS(&Vs[bi][s * 8]), 16, 0, 0);
    }
  };

  f32x4 oacc[4];
#pragma unroll
  for (int d = 0; d < 4; d++) oacc[d] = {0.f, 0.f, 0.f, 0.f};
  f32x4 lacc = {0.f, 0.f, 0.f, 0.f};
  float mst = -INFINITY;

  const int nt = qt + 1;
  STAGE(0, 0);
  int cur = 0;

  for (int tt = 0; tt < nt; tt++) {
    __syncthreads();  // implicit vmcnt(0): tile tt staged; buffer cur^1 free
    if (tt + 1 < nt) STAGE((tt + 1) * 64, cur ^ 1);
    const int kv0 = tt * 64;
    const _Float16* Kb = Ks[cur];
    const _Float16* Vb = Vs[cur];

    // S^T = K Q^T : A = K rows (m=kv), B = Q (n=q). 4 kv-frags x 2 k-steps.
    f32x4 sf[4];
#pragma unroll
    for (int nf = 0; nf < 4; nf++) sf[nf] = {0.f, 0.f, 0.f, 0.f};
    __builtin_amdgcn_s_setprio(1);
#pragma unroll
    for (int ks = 0; ks < 2; ks++)
#pragma unroll
      for (int nf = 0; nf < 4; nf++) {
        const hv8 kf = *reinterpret_cast<const hv8*>(
            Kb + (nf * 16 + lr) * 64 + (((ks * 4 + g) ^ (lr & 7)) * 8));
        sf[nf] = __builtin_amdgcn_mfma_f32_16x16x32_f16(kf, qf[ks], sf[nf], 0, 0, 0);
      }
    __builtin_amdgcn_s_setprio(0);

    // softmax (base-2, in-register, shfl-free steady state)
    const bool diag = (tt == nt - 1);
    float p[4][4];
#pragma unroll
    for (int nf = 0; nf < 4; nf++)
#pragma unroll
      for (int jj = 0; jj < 4; jj++) {
        float xv = sf[nf][jj];
        if (diag && (kv0 + nf * 16 + g * 4 + jj > qg)) xv = -INFINITY;
        p[nf][jj] = xv;
      }
    float r4[4];
#pragma unroll
    for (int nf = 0; nf < 4; nf++)
      r4[nf] = fmaxf(fmaxf(p[nf][0], p[nf][1]), fmaxf(p[nf][2], p[nf][3]));
    const float rm = fmaxf(fmaxf(r4[0], r4[1]), fmaxf(r4[2], r4[3]));
    if (!__all(rm <= mst + 8.0f)) {
      float rw = fmaxf(rm, __shfl_xor(rm, 16));
      rw = fmaxf(rw, __shfl_xor(rw, 32));
      const float mn = fmaxf(mst, rw);
      const float corr = fexp2(mst - mn);  // first tile: exp2(-inf)=0
#pragma unroll
      for (int d = 0; d < 4; d++) oacc[d] *= corr;
      lacc *= corr;
      mst = mn;
    }
#pragma unroll
    for (int nf = 0; nf < 4; nf++)
#pragma unroll
      for (int jj = 0; jj < 4; jj++) p[nf][jj] = fexp2(p[nf][jj] - mst);

    // pf[ks][i] = P[qg][kv0 + ks*32 + (i>>2)*16 + g*4 + (i&3)]  (pi-permuted, lane-local)
    hv8 pf[2];
#pragma unroll
    for (int ks = 0; ks < 2; ks++) {
      const auto c0 = __builtin_amdgcn_cvt_pkrtz(p[2 * ks][0], p[2 * ks][1]);
      const auto c1 = __builtin_amdgcn_cvt_pkrtz(p[2 * ks][2], p[2 * ks][3]);
      const auto c2 = __builtin_amdgcn_cvt_pkrtz(p[2 * ks + 1][0], p[2 * ks + 1][1]);
      const auto c3 = __builtin_amdgcn_cvt_pkrtz(p[2 * ks + 1][2], p[2 * ks + 1][3]);
      pf[ks][0] = (_Float16)c0[0]; pf[ks][1] = (_Float16)c0[1];
      pf[ks][2] = (_Float16)c1[0]; pf[ks][3] = (_Float16)c1[1];
      pf[ks][4] = (_Float16)c2[0]; pf[ks][5] = (_Float16)c2[1];
      pf[ks][6] = (_Float16)c3[0]; pf[ks][7] = (_Float16)c3[1];
    }

    // O^T += V^T P^T (b128 swizzled A-frags); l += ones * P
    __builtin_amdgcn_s_setprio(1);
#pragma unroll
    for (int dblk = 0; dblk < 4; dblk++) {
      const int row = dblk * 16 + lr;
#pragma unroll
      for (int ks = 0; ks < 2; ks++) {
        const hv8 vtf = *reinterpret_cast<const hv8*>(
            Vb + row * 64 + (((ks * 4 + g) ^ (row & 7)) * 8));
        oacc[dblk] = __builtin_amdgcn_mfma_f32_16x16x32_f16(vtf, pf[ks], oacc[dblk], 0, 0, 0);
      }
    }
#pragma unroll
    for (int ks = 0; ks < 2; ks++)
      lacc = __builtin_amdgcn_mfma_f32_16x16x32_f16(onesf, pf[ks], lacc, 0, 0, 0);
    __builtin_amdgcn_s_setprio(0);
    cur ^= 1;
  }

  // epilogue: oacc[dblk][j] = O^T[d=dblk*16+g*4+j][qg]; l = lacc[0]
  const float inv = 1.0f / lacc[0];
#pragma unroll
  for (int dblk = 0; dblk < 4; dblk++) {
    hv4 o;
#pragma unroll
    for (int jj = 0; jj < 4; jj++) o[jj] = (_Float16)(oacc[dblk][jj] * inv);
    *reinterpret_cast<hv4*>(Op + (size_t)qg * 1024 + dblk * 16 + g * 4) = o;
  }
}

extern "C" void kernel_launch(void* const* d_in, const int* in_sizes, int n_in,
                              void* d_out, int out_size, void* d_ws, size_t ws_size,
                              hipStream_t stream) {
  const float* x = (const float*)d_in[0];
  const float* wq = (const float*)d_in[1];
  const float* wk = (const float*)d_in[2];
  const float* wv = (const float*)d_in[3];
  const float* wo = (const float*)d_in[4];
  float* out = (float*)d_out;
  char* ws = (char*)d_ws;
  const size_t MB = 1ull << 20;
  _Float16* xb   = (_Float16*)(ws + 0 * MB);   // 8 MB (A operand for QKV gemm)
  _Float16* wqkv = (_Float16*)(ws + 8 * MB);   // 6 MB (wq|wk|wv contiguous rows)
  _Float16* wob  = (_Float16*)(ws + 14 * MB);  // 2 MB
  _Float16* QKb  = (_Float16*)(ws + 16 * MB);  // 16 MB [4096][2048] Q|K compact
  _Float16* Vtb  = (_Float16*)(ws + 32 * MB);  // 8 MB  [32][64][2048] pi-permuted
  float2*   rtab = (float2*)(ws + 40 * MB);    // 512 KB cos/sin table
  _Float16* Ab   = (_Float16*)(ws + 0 * MB);   // 8 MB  (reuses xb after QKV gemm)

  prep_kernel<<<8448, 256, 0, stream>>>(x, wq, wk, wv, wo, xb, wqkv, wob, rtab);

  // fused Q|K|V projection + V-transpose (rope applied separately on compact QK)
  qkv_gemm_kernel<<<dim3(24, 32), 256, 0, stream>>>(xb, wqkv, QKb, Vtb);

  rope_qk_kernel<<<4096, 256, 0, stream>>>(QKb, rtab);

  attn_kernel<<<1024, 256, 0, stream>>>(QKb, Vtb, Ab);

  gemm_nt<64, float><<<dim3(8, 64), 256, 0, stream>>>(Ab, wob, out, 4096, 1024, 1024);
}

// Round 19
// 104.261 us; speedup vs baseline: 1.1282x; 1.0091x over previous
//
#include <hip/hip_runtime.h>
#include <math.h>

typedef _Float16 hv8 __attribute__((ext_vector_type(8)));
typedef _Float16 hv4 __attribute__((ext_vector_type(4)));
typedef _Float16 hv2 __attribute__((ext_vector_type(2)));
typedef float f32x4 __attribute__((ext_vector_type(4)));

#define LDS_AS(p) ((__attribute__((address_space(3))) void*)(p))
#define GLB_AS(p) ((const __attribute__((address_space(1))) void*)(p))

// single-instruction base-2 exp (bypasses OCML; v_exp_f32 is the native trans op)
__device__ __forceinline__ float fexp2(float x) {
  float r;
  asm("v_exp_f32 %0, %1" : "=v"(r) : "v"(x));
  return r;
}

// ---------------- prep: rope cos/sin table + fp32->fp16 converts, one launch ----------------
__global__ void prep_kernel(const float* __restrict__ x, const float* __restrict__ wq,
                            const float* __restrict__ wk, const float* __restrict__ wv,
                            const float* __restrict__ wo, _Float16* __restrict__ xb,
                            _Float16* __restrict__ wqkv, _Float16* __restrict__ wob,
                            float2* __restrict__ tab) {
  const int bid = blockIdx.x;
  if (bid < 256) {
    const int idx = bid * 256 + threadIdx.x;  // 65536
    const int pos = idx >> 5, i = idx & 31;
    const float freq = exp2f((float)i * (-13.287712379549449f / 32.0f));
    float s, c;
    sincosf((float)pos * freq, &s, &c);
    tab[idx] = make_float2(c, s);
    return;
  }
  const int i = ((bid - 256) * 256 + threadIdx.x) * 4;  // 0 .. 8M-4
  const float* s;
  _Float16* d;
  int r;
  if (i < 4194304) {  // x segment (block-uniform: 1M boundaries)
    s = x; d = xb; r = i;
  } else {
    const int j = i - 4194304;
    const int seg = j >> 20;
    r = j & 1048575;
    s = (seg == 0) ? wq : (seg == 1) ? wk : (seg == 2) ? wv : wo;
    d = (seg < 3) ? (wqkv + (size_t)seg * 1048576) : wob;
  }
  const float4 v = *reinterpret_cast<const float4*>(s + r);
  hv4 o = {(_Float16)v.x, (_Float16)v.y, (_Float16)v.z, (_Float16)v.w};
  *reinterpret_cast<hv4*>(d + r) = o;
}

// ---------------- fused QKV projection GEMM, reg-frag prefetch K-loop ---------------- (R15)
__global__ __launch_bounds__(256, 3) void qkv_gemm_kernel(const _Float16* __restrict__ A,
                                                          const _Float16* __restrict__ B,
                                                          _Float16* __restrict__ QK,
                                                          _Float16* __restrict__ Vt) {
  constexpr int K = 1024;
  __shared__ __align__(16) _Float16 As[128 * 64];
  __shared__ __align__(16) _Float16 Bs[128 * 64];
  const int t = threadIdx.x;
  const int w = t >> 6, lane = t & 63;
  const int wr = w >> 1, wc = w & 1;
  const int g = lane >> 4, lr = lane & 15;
  const int mBase = blockIdx.y * 128, nBase = blockIdx.x * 128;

  f32x4 acc[4][4];
#pragma unroll
  for (int a = 0; a < 4; a++)
#pragma unroll
    for (int bb = 0; bb < 4; bb++) acc[a][bb] = {0.f, 0.f, 0.f, 0.f};

  auto STAGE = [&](int k0) {
#pragma unroll
    for (int i = 0; i < 4; i++) {
      const int s = i * 256 + t;
      const int r = s >> 3;
      const int cs = ((s & 7) ^ (r & 7)) * 8;
      __builtin_amdgcn_global_load_lds(GLB_AS(A + (size_t)(mBase + r) * K + k0 + cs),
                                       LDS_AS(As + s * 8), 16, 0, 0);
      __builtin_amdgcn_global_load_lds(GLB_AS(B + (size_t)(nBase + r) * K + k0 + cs),
                                       LDS_AS(Bs + s * 8), 16, 0, 0);
    }
  };

  STAGE(0);
  for (int kt = 0; kt < K / 64; kt++) {
    __syncthreads();  // implicit vmcnt(0): staging of tile kt complete
    hv8 af[2][4], bfr[2][4];
#pragma unroll
    for (int ks = 0; ks < 2; ks++) {
#pragma unroll
      for (int mi = 0; mi < 4; mi++) {
        const int ra = wr * 64 + mi * 16 + lr;
        af[ks][mi] = *reinterpret_cast<const hv8*>(As + ra * 64 + (((ks * 4 + g) ^ (ra & 7)) * 8));
      }
#pragma unroll
      for (int ni = 0; ni < 4; ni++) {
        const int rb = wc * 64 + ni * 16 + lr;
        bfr[ks][ni] = *reinterpret_cast<const hv8*>(Bs + rb * 64 + (((ks * 4 + g) ^ (rb & 7)) * 8));
      }
    }
    __syncthreads();  // all waves done reading LDS; buffer free for next staging
    if (kt + 1 < K / 64) STAGE((kt + 1) * 64);
#pragma unroll
    for (int ks = 0; ks < 2; ks++)
#pragma unroll
      for (int mi = 0; mi < 4; mi++)
#pragma unroll
        for (int ni = 0; ni < 4; ni++)
          acc[mi][ni] = __builtin_amdgcn_mfma_f32_16x16x32_f16(af[ks][mi], bfr[ks][ni], acc[mi][ni], 0, 0, 0);
  }

  const int rowBase = mBase + wr * 64;
  const int colBase = nBase + wc * 64;
  if (nBase < 2048) {
    // ---- Q|K: plain store to compact QK [4096][2048] ----
#pragma unroll
    for (int mi = 0; mi < 4; mi++) {
#pragma unroll
      for (int j = 0; j < 4; j++) {
        const size_t row = rowBase + mi * 16 + g * 4 + j;
#pragma unroll
        for (int ni = 0; ni < 4; ni++) {
          const int col = colBase + ni * 16 + lr;
          QK[row * 2048 + col] = (_Float16)acc[mi][ni][j];
        }
      }
    }
  } else {
    // ---- V: pi-permuted transpose store to Vt[bh][d][2048] ----
    const int b = rowBase >> 11;
    const int tok0 = rowBase & 2047;
#pragma unroll
    for (int ni = 0; ni < 4; ni++) {
      const int cc = colBase - 2048 + ni * 16 + lr;
      const int h = cc >> 6, d = cc & 63;
      _Float16* vp = Vt + ((size_t)(b * 16 + h) * 64 + d) * 2048 + tok0 + g * 8;
      hv8 o1, o2;
#pragma unroll
      for (int j = 0; j < 4; j++) {
        o1[j] = (_Float16)acc[0][ni][j];
        o1[4 + j] = (_Float16)acc[1][ni][j];
        o2[j] = (_Float16)acc[2][ni][j];
        o2[4 + j] = (_Float16)acc[3][ni][j];
      }
      *reinterpret_cast<hv8*>(vp) = o1;
      *reinterpret_cast<hv8*>(vp + 32) = o2;
    }
  }
}

// ---------------- RoPE on K only (QK cols 1024..2047), table-driven, hv8 ----------------
// Q-rope moved into attn's Q-fragment load (lane-local, once per block). 2048 blocks x 256
// threads x 8 elems = 4M = the K half exactly.
__global__ void rope_k_kernel(_Float16* __restrict__ QK, const float2* __restrict__ tab) {
  const int idx = blockIdx.x * 256 + threadIdx.x;  // 512K threads
  const int row = idx >> 7;          // 0..4095
  const int c8 = (idx & 127) * 8;    // col within K half (4 rope pairs)
  const int pos = row & 2047;
  const int i0 = (c8 & 63) >> 1;
  const size_t off = (size_t)row * 2048 + 1024 + c8;
  hv8 v = *reinterpret_cast<const hv8*>(QK + off);
  const float2* tp = tab + pos * 32 + i0;
  const float4 t01 = *reinterpret_cast<const float4*>(tp);
  const float4 t23 = *reinterpret_cast<const float4*>(tp + 2);
  const float c[4] = {t01.x, t01.z, t23.x, t23.z};
  const float s[4] = {t01.y, t01.w, t23.y, t23.w};
#pragma unroll
  for (int k = 0; k < 4; k++) {
    const float e = (float)v[2 * k], o = (float)v[2 * k + 1];
    v[2 * k] = (_Float16)(e * c[k] - o * s[k]);
    v[2 * k + 1] = (_Float16)(e * s[k] + o * c[k]);
  }
  *reinterpret_cast<hv8*>(QK + off) = v;
}

// ---------------- NT GEMM (out-projection), reg-frag prefetch K-loop ---------------- (R15)
template <int BM, typename OutT>
__global__ __launch_bounds__(256, 2) void gemm_nt(const _Float16* __restrict__ A,
                                                  const _Float16* __restrict__ B,
                                                  OutT* __restrict__ C,
                                                  const int M, const int N, const int K) {
  constexpr int MI = BM / 32;
  constexpr int ALOADS = BM / 32;
  __shared__ __align__(16) _Float16 As[BM * 64];
  __shared__ __align__(16) _Float16 Bs[128 * 64];
  const int t = threadIdx.x;
  const int w = t >> 6, lane = t & 63;
  const int wr = w >> 1, wc = w & 1;
  const int g = lane >> 4, lr = lane & 15;
  const int mBase = blockIdx.y * BM, nBase = blockIdx.x * 128;

  f32x4 acc[MI][4];
#pragma unroll
  for (int a = 0; a < MI; a++)
#pragma unroll
    for (int bb = 0; bb < 4; bb++) acc[a][bb] = {0.f, 0.f, 0.f, 0.f};

  auto STAGE = [&](int k0) {
#pragma unroll
    for (int i = 0; i < ALOADS; i++) {
      const int s = i * 256 + t;
      const int r = s >> 3;
      const int cs = ((s & 7) ^ (r & 7)) * 8;
      __builtin_amdgcn_global_load_lds(GLB_AS(A + (size_t)(mBase + r) * K + k0 + cs),
                                       LDS_AS(As + s * 8), 16, 0, 0);
    }
#pragma unroll
    for (int i = 0; i < 4; i++) {
      const int s = i * 256 + t;
      const int r = s >> 3;
      const int cs = ((s & 7) ^ (r & 7)) * 8;
      __builtin_amdgcn_global_load_lds(GLB_AS(B + (size_t)(nBase + r) * K + k0 + cs),
                                       LDS_AS(Bs + s * 8), 16, 0, 0);
    }
  };

  STAGE(0);
  const int NT = K / 64;
  for (int kt = 0; kt < NT; kt++) {
    __syncthreads();  // implicit vmcnt(0): staging of tile kt complete
    hv8 af[2][MI], bfr[2][4];
#pragma unroll
    for (int ks = 0; ks < 2; ks++) {
#pragma unroll
      for (int mi = 0; mi < MI; mi++) {
        const int ra = wr * (BM / 2) + mi * 16 + lr;
        af[ks][mi] = *reinterpret_cast<const hv8*>(As + ra * 64 + (((ks * 4 + g) ^ (ra & 7)) * 8));
      }
#pragma unroll
      for (int ni = 0; ni < 4; ni++) {
        const int rb = wc * 64 + ni * 16 + lr;
        bfr[ks][ni] = *reinterpret_cast<const hv8*>(Bs + rb * 64 + (((ks * 4 + g) ^ (rb & 7)) * 8));
      }
    }
    __syncthreads();  // LDS free
    if (kt + 1 < NT) STAGE((kt + 1) * 64);
#pragma unroll
    for (int ks = 0; ks < 2; ks++)
#pragma unroll
      for (int mi = 0; mi < MI; mi++)
#pragma unroll
        for (int ni = 0; ni < 4; ni++)
          acc[mi][ni] = __builtin_amdgcn_mfma_f32_16x16x32_f16(af[ks][mi], bfr[ks][ni], acc[mi][ni], 0, 0, 0);
  }
#pragma unroll
  for (int mi = 0; mi < MI; mi++) {
#pragma unroll
    for (int j = 0; j < 4; j++) {
      const size_t row = mBase + wr * (BM / 2) + mi * 16 + g * 4 + j;
#pragma unroll
      for (int ni = 0; ni < 4; ni++) {
        const int col = nBase + wc * 64 + ni * 16 + lr;
        C[row * N + col] = (OutT)acc[mi][ni][j];
      }
    }
  }
}

// ---------------- flash causal attention, 4 blocks/CU, CU-balanced qt mapping ----------------
// R18 structure + Q-rope fused into the Q-fragment load: each lane ropes its own q-row's
// 16 elements (pairs are lane-local in the B-frag layout), 4 float4 tab reads once per
// block; 1/sqrt(d)*log2e scale folded into the same fma chain. K comes pre-roped.
__global__ __launch_bounds__(256, 4) void attn_kernel(const _Float16* __restrict__ QK,
                                                      const _Float16* __restrict__ Vt,
                                                      const float2* __restrict__ tab,
                                                      _Float16* __restrict__ O) {
  __shared__ __align__(16) _Float16 Ks[2][64 * 64];
  __shared__ __align__(16) _Float16 Vs[2][64 * 64];
  const int t = threadIdx.x;
  const int w = t >> 6, lane = t & 63;
  const int g = lane >> 4, lr = lane & 15;
  // CU-balanced q-tile mapping
  const int id = blockIdx.x;
  const int j = id >> 8, r = id & 255;
  const int bh = r & 31, base = r >> 5;
  const int half = j >> 1;
  const int qt = (j & 1) ? (31 - base - 8 * half) : (base + 8 * half);
  const int m0 = qt * 64;
  const int b = bh >> 4, h = bh & 15;
  const _Float16* Qp = QK + (size_t)b * 2048 * 2048 + h * 64;
  const _Float16* Kp = Qp + 1024;
  const _Float16* Vp = Vt + (size_t)bh * 64 * 2048;
  _Float16* Op = O + (size_t)b * 2048 * 1024 + h * 64;

  const int qg = m0 + w * 16 + lr;  // this lane's q row
  const int pos = qg & 2047;

  // Q B-frag (n=q, k=g*8+i): load, rope (pairs lane-local), scale by (1/8)*log2(e)
  hv8 qf[2];
#pragma unroll
  for (int ks = 0; ks < 2; ks++) {
    const hv8 v = *reinterpret_cast<const hv8*>(Qp + (size_t)qg * 2048 + ks * 32 + g * 8);
    const float2* tp = tab + pos * 32 + ks * 16 + g * 4;
    const float4 t01 = *reinterpret_cast<const float4*>(tp);
    const float4 t23 = *reinterpret_cast<const float4*>(tp + 2);
    const float c[4] = {t01.x, t01.z, t23.x, t23.z};
    const float s[4] = {t01.y, t01.w, t23.y, t23.w};
#pragma unroll
    for (int k = 0; k < 4; k++) {
      const float e = (float)v[2 * k], o = (float)v[2 * k + 1];
      qf[ks][2 * k] = (_Float16)((e * c[k] - o * s[k]) * 0.18033688f);
      qf[ks][2 * k + 1] = (_Float16)((e * s[k] + o * c[k]) * 0.18033688f);
    }
  }

  const hv8 onesf = {(_Float16)1.0f, (_Float16)1.0f, (_Float16)1.0f, (_Float16)1.0f,
                     (_Float16)1.0f, (_Float16)1.0f, (_Float16)1.0f, (_Float16)1.0f};

  auto STAGE = [&](int kv0, int bi) {
#pragma unroll
    for (int i = 0; i < 2; i++) {
      const int s = i * 256 + t;
      const int rr = s >> 3;
      const int cs = ((s & 7) ^ (rr & 7)) * 8;
      __builtin_amdgcn_global_load_lds(GLB_AS(Kp + (size_t)(kv0 + rr) * 2048 + cs),
                                       LDS_AS(&Ks[bi][s * 8]), 16, 0, 0);
      __builtin_amdgcn_global_load_lds(GLB_AS(Vp + (size_t)rr * 2048 + kv0 + cs),
                                       LDS_AS(&Vs[bi][s * 8]), 16, 0, 0);
    }
  };

  f32x4 oacc[4];
#pragma unroll
  for (int d = 0; d < 4; d++) oacc[d] = {0.f, 0.f, 0.f, 0.f};
  f32x4 lacc = {0.f, 0.f, 0.f, 0.f};
  float mst = -INFINITY;

  const int nt = qt + 1;
  STAGE(0, 0);
  int cur = 0;

  for (int tt = 0; tt < nt; tt++) {
    __syncthreads();  // implicit vmcnt(0): tile tt staged; buffer cur^1 free
    if (tt + 1 < nt) STAGE((tt + 1) * 64, cur ^ 1);
    const int kv0 = tt * 64;
    const _Float16* Kb = Ks[cur];
    const _Float16* Vb = Vs[cur];

    // S^T = K Q^T : A = K rows (m=kv), B = Q (n=q). 4 kv-frags x 2 k-steps.
    f32x4 sf[4];
#pragma unroll
    for (int nf = 0; nf < 4; nf++) sf[nf] = {0.f, 0.f, 0.f, 0.f};
    __builtin_amdgcn_s_setprio(1);
#pragma unroll
    for (int ks = 0; ks < 2; ks++)
#pragma unroll
      for (int nf = 0; nf < 4; nf++) {
        const hv8 kf = *reinterpret_cast<const hv8*>(
            Kb + (nf * 16 + lr) * 64 + (((ks * 4 + g) ^ (lr & 7)) * 8));
        sf[nf] = __builtin_amdgcn_mfma_f32_16x16x32_f16(kf, qf[ks], sf[nf], 0, 0, 0);
      }
    __builtin_amdgcn_s_setprio(0);

    // softmax (base-2, in-register, shfl-free steady state)
    const bool diag = (tt == nt - 1);
    float p[4][4];
#pragma unroll
    for (int nf = 0; nf < 4; nf++)
#pragma unroll
      for (int jj = 0; jj < 4; jj++) {
        float xv = sf[nf][jj];
        if (diag && (kv0 + nf * 16 + g * 4 + jj > qg)) xv = -INFINITY;
        p[nf][jj] = xv;
      }
    float r4[4];
#pragma unroll
    for (int nf = 0; nf < 4; nf++)
      r4[nf] = fmaxf(fmaxf(p[nf][0], p[nf][1]), fmaxf(p[nf][2], p[nf][3]));
    const float rm = fmaxf(fmaxf(r4[0], r4[1]), fmaxf(r4[2], r4[3]));
    if (!__all(rm <= mst + 8.0f)) {
      float rw = fmaxf(rm, __shfl_xor(rm, 16));
      rw = fmaxf(rw, __shfl_xor(rw, 32));
      const float mn = fmaxf(mst, rw);
      const float corr = fexp2(mst - mn);  // first tile: exp2(-inf)=0
#pragma unroll
      for (int d = 0; d < 4; d++) oacc[d] *= corr;
      lacc *= corr;
      mst = mn;
    }
#pragma unroll
    for (int nf = 0; nf < 4; nf++)
#pragma unroll
      for (int jj = 0; jj < 4; jj++) p[nf][jj] = fexp2(p[nf][jj] - mst);

    // pf[ks][i] = P[qg][kv0 + ks*32 + (i>>2)*16 + g*4 + (i&3)]  (pi-permuted, lane-local)
    hv8 pf[2];
#pragma unroll
    for (int ks = 0; ks < 2; ks++) {
      const auto c0 = __builtin_amdgcn_cvt_pkrtz(p[2 * ks][0], p[2 * ks][1]);
      const auto c1 = __builtin_amdgcn_cvt_pkrtz(p[2 * ks][2], p[2 * ks][3]);
      const auto c2 = __builtin_amdgcn_cvt_pkrtz(p[2 * ks + 1][0], p[2 * ks + 1][1]);
      const auto c3 = __builtin_amdgcn_cvt_pkrtz(p[2 * ks + 1][2], p[2 * ks + 1][3]);
      pf[ks][0] = (_Float16)c0[0]; pf[ks][1] = (_Float16)c0[1];
      pf[ks][2] = (_Float16)c1[0]; pf[ks][3] = (_Float16)c1[1];
      pf[ks][4] = (_Float16)c2[0]; pf[ks][5] = (_Float16)c2[1];
      pf[ks][6] = (_Float16)c3[0]; pf[ks][7] = (_Float16)c3[1];
    }

    // O^T += V^T P^T (b128 swizzled A-frags); l += ones * P
    __builtin_amdgcn_s_setprio(1);
#pragma unroll
    for (int dblk = 0; dblk < 4; dblk++) {
      const int row = dblk * 16 + lr;
#pragma unroll
      for (int ks = 0; ks < 2; ks++) {
        const hv8 vtf = *reinterpret_cast<const hv8*>(
            Vb + row * 64 + (((ks * 4 + g) ^ (row & 7)) * 8));
        oacc[dblk] = __builtin_amdgcn_mfma_f32_16x16x32_f16(vtf, pf[ks], oacc[dblk], 0, 0, 0);
      }
    }
#pragma unroll
    for (int ks = 0; ks < 2; ks++)
      lacc = __builtin_amdgcn_mfma_f32_16x16x32_f16(onesf, pf[ks], lacc, 0, 0, 0);
    __builtin_amdgcn_s_setprio(0);
    cur ^= 1;
  }

  // epilogue: oacc[dblk][j] = O^T[d=dblk*16+g*4+j][qg]; l = lacc[0]
  const float inv = 1.0f / lacc[0];
#pragma unroll
  for (int dblk = 0; dblk < 4; dblk++) {
    hv4 o;
#pragma unroll
    for (int jj = 0; jj < 4; jj++) o[jj] = (_Float16)(oacc[dblk][jj] * inv);
    *reinterpret_cast<hv4*>(Op + (size_t)qg * 1024 + dblk * 16 + g * 4) = o;
  }
}

extern "C" void kernel_launch(void* const* d_in, const int* in_sizes, int n_in,
                              void* d_out, int out_size, void* d_ws, size_t ws_size,
                              hipStream_t stream) {
  const float* x = (const float*)d_in[0];
  const float* wq = (const float*)d_in[1];
  const float* wk = (const float*)d_in[2];
  const float* wv = (const float*)d_in[3];
  const float* wo = (const float*)d_in[4];
  float* out = (float*)d_out;
  char* ws = (char*)d_ws;
  const size_t MB = 1ull << 20;
  _Float16* xb   = (_Float16*)(ws + 0 * MB);   // 8 MB (A operand for QKV gemm)
  _Float16* wqkv = (_Float16*)(ws + 8 * MB);   // 6 MB (wq|wk|wv contiguous rows)
  _Float16* wob  = (_Float16*)(ws + 14 * MB);  // 2 MB
  _Float16* QKb  = (_Float16*)(ws + 16 * MB);  // 16 MB [4096][2048] Q|K compact
  _Float16* Vtb  = (_Float16*)(ws + 32 * MB);  // 8 MB  [32][64][2048] pi-permuted
  float2*   rtab = (float2*)(ws + 40 * MB);    // 512 KB cos/sin table
  _Float16* Ab   = (_Float16*)(ws + 0 * MB);   // 8 MB  (reuses xb after QKV gemm)

  prep_kernel<<<8448, 256, 0, stream>>>(x, wq, wk, wv, wo, xb, wqkv, wob, rtab);

  // fused Q|K|V projection + V-transpose (K roped by rope_k; Q roped inside attn)
  qkv_gemm_kernel<<<dim3(24, 32), 256, 0, stream>>>(xb, wqkv, QKb, Vtb);

  rope_k_kernel<<<2048, 256, 0, stream>>>(QKb, rtab);

  attn_kernel<<<1024, 256, 0, stream>>>(QKb, Vtb, rtab, Ab);

  gemm_nt<64, float><<<dim3(8, 64), 256, 0, stream>>>(Ab, wob, out, 4096, 1024, 1024);
}